// Round 1
// baseline (667.306 us; speedup 1.0000x reference)
//
#include <hip/hip_runtime.h>
#include <stdint.h>

// GroupedQueryLatentAttention on MI355X (gfx950).
// B=2 S=2048 HID=2048 HEADS=16 D=128 GROUPS=4 LATENT=512 KV=512.
// Pipeline: fp32->bf16 convert/transpose prep, bf16 MFMA GEMMs (m97 structure),
// flash attention with swapped-QK^T in-lane softmax, fp32 output GEMM.

#define DEV static __device__ __forceinline__

using short8 = __attribute__((ext_vector_type(8))) short;
using f32x4  = __attribute__((ext_vector_type(4))) float;

typedef __attribute__((address_space(1))) void gvoid;
typedef __attribute__((address_space(3))) void lvoid;

DEV unsigned short f2b(float f) {
  unsigned u = __builtin_bit_cast(unsigned, f);
  unsigned r = (u + 0x7fffu + ((u >> 16) & 1u)) >> 16;
  return (unsigned short)r;
}
DEV float b2f(unsigned short s) {
  unsigned u = ((unsigned)s) << 16;
  return __builtin_bit_cast(float, u);
}
DEV float as_f32(float v) { return v; }
DEV float as_f32(unsigned short v) { return b2f(v); }

// async global->LDS, 16B per lane. LDS dest must be uniform_base + lane*16.
DEV void async16(const void* g, void* l) {
  __builtin_amdgcn_global_load_lds((gvoid*)(uintptr_t)g,
                                   (lvoid*)(uint32_t)(uintptr_t)l, 16, 0, 0);
}

// ---------------- elementwise fp32 -> bf16 ----------------
__global__ __launch_bounds__(256) void cvt_f32_bf16(
    const float* __restrict__ in, unsigned short* __restrict__ out, long n) {
  long i = ((long)blockIdx.x * 256 + threadIdx.x) * 8;
  if (i >= n) return;
  float4 a = *(const float4*)(in + i);
  float4 b = *(const float4*)(in + i + 4);
  short8 o;
  o[0] = (short)f2b(a.x); o[1] = (short)f2b(a.y);
  o[2] = (short)f2b(a.z); o[3] = (short)f2b(a.w);
  o[4] = (short)f2b(b.x); o[5] = (short)f2b(b.y);
  o[6] = (short)f2b(b.z); o[7] = (short)f2b(b.w);
  *(short8*)(out + i) = o;
}

// ---------------- transpose [R][C] -> [C][R], out bf16 ----------------
template <typename TIN>
__global__ __launch_bounds__(256) void transpose_to_bf16(
    const TIN* __restrict__ in, unsigned short* __restrict__ out, int R, int C) {
  __shared__ float tile[32][33];
  size_t batch = (size_t)blockIdx.z * (size_t)R * C;
  int bc = blockIdx.x * 32, br = blockIdx.y * 32;
  int tx = threadIdx.x & 31, ty0 = threadIdx.x >> 5;
#pragma unroll
  for (int ty = ty0; ty < 32; ty += 8)
    tile[ty][tx] = as_f32(in[batch + (size_t)(br + ty) * C + bc + tx]);
  __syncthreads();
#pragma unroll
  for (int ty = ty0; ty < 32; ty += 8)
    out[batch + (size_t)(bc + ty) * R + br + tx] = f2b(tile[tx][ty]);
}

// ---------------- GEMM: C[M,N] = A[M,K] * Bt[N,K]^T + bias, (opt) *scale ----
// 128x128 tile, 4 waves (each 64x64 = 4x4 mfma frags), BK=32, global_load_lds.
template <int OUT_F32>
__global__ __launch_bounds__(256) void gemm_bt(
    const unsigned short* __restrict__ A, const unsigned short* __restrict__ Bt,
    const float* __restrict__ bias, void* __restrict__ Cout,
    int M, int N, int K, float scale) {
  __shared__ unsigned short As[128 * 32];
  __shared__ unsigned short Bs[128 * 32];
  int tid = threadIdx.x;
  int lane = tid & 63, wave = tid >> 6;
  int wr = wave >> 1, wc = wave & 1;
  int lq = lane & 15, grp = lane >> 4;
  int brow = blockIdx.y * 128, bcol = blockIdx.x * 128;

  f32x4 acc[4][4] = {};

  for (int k0 = 0; k0 < K; k0 += 32) {
    // stage A/B tiles: 128x32 bf16 = 8KB each; 2 x 16B issues per thread each
    {
      int e0 = tid * 8;
      int r0 = e0 >> 5, c0 = e0 & 31;
      async16(A + (size_t)(brow + r0) * K + k0 + c0, As + e0);
      async16(Bt + (size_t)(bcol + r0) * K + k0 + c0, Bs + e0);
      int e1 = (256 + tid) * 8;
      int r1 = e1 >> 5, c1 = e1 & 31;
      async16(A + (size_t)(brow + r1) * K + k0 + c1, As + e1);
      async16(Bt + (size_t)(bcol + r1) * K + k0 + c1, Bs + e1);
    }
    __syncthreads();  // compiler drains vmcnt before barrier

    short8 af[4], bf[4];
#pragma unroll
    for (int m = 0; m < 4; m++)
      af[m] = *(const short8*)(As + (wr * 64 + m * 16 + lq) * 32 + grp * 8);
#pragma unroll
    for (int n = 0; n < 4; n++)
      bf[n] = *(const short8*)(Bs + (wc * 64 + n * 16 + lq) * 32 + grp * 8);
#pragma unroll
    for (int m = 0; m < 4; m++)
#pragma unroll
      for (int n = 0; n < 4; n++)
        acc[m][n] = __builtin_amdgcn_mfma_f32_16x16x32_bf16(af[m], bf[n], acc[m][n], 0, 0, 0);
    __syncthreads();
  }

  // epilogue: C row = (lane>>4)*4 + r, col = lane&15 within each 16x16 frag
#pragma unroll
  for (int n = 0; n < 4; n++) {
    int col = bcol + wc * 64 + n * 16 + lq;
    float bv = bias[col];
#pragma unroll
    for (int m = 0; m < 4; m++) {
#pragma unroll
      for (int r = 0; r < 4; r++) {
        int row = brow + wr * 64 + m * 16 + grp * 4 + r;
        float v = (acc[m][n][r] + bv) * scale;
        if (OUT_F32)
          ((float*)Cout)[(size_t)row * N + col] = v;
        else
          ((unsigned short*)Cout)[(size_t)row * N + col] = f2b(v);
      }
    }
  }
}

// ---------------- flash attention ----------------
// grid (S/64, HEADS, B), block 256 = 4 independent waves, each owns 16 q-rows.
// Swapped QK^T: S^T = mfma(K, Q) -> each lane holds 8 scores of ONE q-row
// (qrow = lane&15, kv = kv0 + (lane>>4)*8 + j) via row-permuted K operand.
// That per-lane layout IS the A-operand layout of the PV 16x16x32 mfma.
__global__ __launch_bounds__(256) void attn_kernel(
    const unsigned short* __restrict__ q,   // [B*S][2048], pre-scaled by 1/sqrt(D)
    const unsigned short* __restrict__ k,   // [B*S][512]
    const unsigned short* __restrict__ vt,  // [(b*4+g)*128 + d][2048] (= V^T per group)
    unsigned short* __restrict__ ctx) {     // [B*S][2048]
  int lane = threadIdx.x & 63, wave = threadIdx.x >> 6;
  int lq = lane & 15, grp = lane >> 4;
  int h = blockIdx.y, b = blockIdx.z, g = h >> 2;
  int qbase = blockIdx.x * 64 + wave * 16;

  // Q fragments (held whole kernel): Q[qbase+lq][h*128 + c*32 + grp*8 .. +8]
  const unsigned short* qp =
      q + ((size_t)(b * 2048 + qbase + lq)) * 2048 + h * 128 + grp * 8;
  short8 qf[4];
#pragma unroll
  for (int c = 0; c < 4; c++) qf[c] = *(const short8*)(qp + c * 32);

  f32x4 o[8] = {};
  float mrun = -3.0e38f, lsum = 0.f;

  const unsigned short* kbase = k + (size_t)b * 2048 * 512 + g * 128 + grp * 8;
  const unsigned short* vtb =
      vt + ((size_t)(b * 4 + g)) * 128 * 2048 + (size_t)lq * 2048;
  int kvperm = ((lq >> 2) * 8) + (lq & 3);  // row permutation pi(lq)

  for (int kv0 = 0; kv0 < 2048; kv0 += 32) {
    f32x4 s[2];
#pragma unroll
    for (int t = 0; t < 2; t++) {
      const unsigned short* kp = kbase + (size_t)(kv0 + kvperm + 4 * t) * 512;
      f32x4 st = {0.f, 0.f, 0.f, 0.f};
#pragma unroll
      for (int c = 0; c < 4; c++) {
        short8 kf = *(const short8*)(kp + c * 32);
        st = __builtin_amdgcn_mfma_f32_16x16x32_bf16(kf, qf[c], st, 0, 0, 0);
      }
      s[t] = st;
    }
    // online softmax; lane's 8 scores all belong to qrow = lq
    float tmax = fmaxf(fmaxf(fmaxf(s[0][0], s[0][1]), fmaxf(s[0][2], s[0][3])),
                       fmaxf(fmaxf(s[1][0], s[1][1]), fmaxf(s[1][2], s[1][3])));
    tmax = fmaxf(tmax, __shfl_xor(tmax, 16));
    tmax = fmaxf(tmax, __shfl_xor(tmax, 32));
    float mnew = fmaxf(mrun, tmax);
    float alpha = __expf(mrun - mnew);
    float p[8], psum = 0.f;
#pragma unroll
    for (int j = 0; j < 8; j++) {
      float e = __expf(s[j >> 2][j & 3] - mnew);
      p[j] = e;
      psum += e;
    }
    lsum = lsum * alpha + psum;
    mrun = mnew;
    // per-output-row alphas (acc rows are qrows grp*4+r)
    float a0 = __shfl(alpha, grp * 4 + 0);
    float a1 = __shfl(alpha, grp * 4 + 1);
    float a2 = __shfl(alpha, grp * 4 + 2);
    float a3 = __shfl(alpha, grp * 4 + 3);
    short8 pf;
#pragma unroll
    for (int j = 0; j < 8; j++) pf[j] = (short)f2b(p[j]);
#pragma unroll
    for (int d0 = 0; d0 < 8; d0++) {
      o[d0][0] *= a0; o[d0][1] *= a1; o[d0][2] *= a2; o[d0][3] *= a3;
      short8 vf = *(const short8*)(vtb + (size_t)(d0 * 16) * 2048 + kv0 + grp * 8);
      o[d0] = __builtin_amdgcn_mfma_f32_16x16x32_bf16(pf, vf, o[d0], 0, 0, 0);
    }
  }
  // finalize: row sums need cross-group combine
  lsum += __shfl_xor(lsum, 16);
  lsum += __shfl_xor(lsum, 32);
  float rinv = 1.0f / lsum;
  float r0 = __shfl(rinv, grp * 4 + 0);
  float r1 = __shfl(rinv, grp * 4 + 1);
  float r2 = __shfl(rinv, grp * 4 + 2);
  float r3 = __shfl(rinv, grp * 4 + 3);

  unsigned short* cp = ctx + ((size_t)(b * 2048 + qbase)) * 2048 + h * 128;
#pragma unroll
  for (int d0 = 0; d0 < 8; d0++) {
    int col = d0 * 16 + lq;
    cp[(size_t)(grp * 4 + 0) * 2048 + col] = f2b(o[d0][0] * r0);
    cp[(size_t)(grp * 4 + 1) * 2048 + col] = f2b(o[d0][1] * r1);
    cp[(size_t)(grp * 4 + 2) * 2048 + col] = f2b(o[d0][2] * r2);
    cp[(size_t)(grp * 4 + 3) * 2048 + col] = f2b(o[d0][3] * r3);
  }
}

// ---------------- host ----------------
extern "C" void kernel_launch(void* const* d_in, const int* in_sizes, int n_in,
                              void* d_out, int out_size, void* d_ws, size_t ws_size,
                              hipStream_t stream) {
  const float* h  = (const float*)d_in[0];
  const float* Wq = (const float*)d_in[1];
  const float* bq = (const float*)d_in[2];
  const float* Wl = (const float*)d_in[3];
  const float* bl = (const float*)d_in[4];
  const float* Wk = (const float*)d_in[5];
  const float* bk = (const float*)d_in[6];
  const float* Wv = (const float*)d_in[7];
  const float* bv = (const float*)d_in[8];
  const float* Wo = (const float*)d_in[9];
  const float* bo = (const float*)d_in[10];
  float* out = (float*)d_out;

  const int M = 4096;  // B*S

  char* w = (char*)d_ws;
  auto take = [&](size_t elems) {
    void* p = (void*)w;
    w += (elems * 2 + 255) & ~(size_t)255;
    return (unsigned short*)p;
  };
  unsigned short* hb  = take(8388608);  // [4096][2048]
  unsigned short* WqT = take(4194304);  // [2048][2048]
  unsigned short* WlT = take(1048576);  // [512][2048]
  unsigned short* WkT = take(262144);   // [512][512]
  unsigned short* WvT = take(262144);   // [512][512]
  unsigned short* WoT = take(4194304);  // [2048][2048]
  unsigned short* qb  = take(8388608);  // [4096][2048]
  unsigned short* lat = take(2097152);  // [4096][512]
  unsigned short* kb  = take(2097152);  // [4096][512]
  unsigned short* vb  = take(2097152);  // [4096][512]
  unsigned short* vtb = take(2097152);  // [2*512][2048]
  unsigned short* ctx = take(8388608);  // [4096][2048]

  // prep: convert + transpose
  cvt_f32_bf16<<<4096, 256, 0, stream>>>(h, hb, 8388608L);
  transpose_to_bf16<float><<<dim3(64, 64, 1), 256, 0, stream>>>(Wq, WqT, 2048, 2048);
  transpose_to_bf16<float><<<dim3(16, 64, 1), 256, 0, stream>>>(Wl, WlT, 2048, 512);
  transpose_to_bf16<float><<<dim3(16, 16, 1), 256, 0, stream>>>(Wk, WkT, 512, 512);
  transpose_to_bf16<float><<<dim3(16, 16, 1), 256, 0, stream>>>(Wv, WvT, 512, 512);
  transpose_to_bf16<float><<<dim3(64, 64, 1), 256, 0, stream>>>(Wo, WoT, 2048, 2048);

  const float scale = 0.08838834764831845f;  // 1/sqrt(128), folded into q
  gemm_bt<0><<<dim3(16, 32), 256, 0, stream>>>(hb, WqT, bq, qb, M, 2048, 2048, scale);
  gemm_bt<0><<<dim3(4, 32), 256, 0, stream>>>(hb, WlT, bl, lat, M, 512, 2048, 1.0f);
  gemm_bt<0><<<dim3(4, 32), 256, 0, stream>>>(lat, WkT, bk, kb, M, 512, 512, 1.0f);
  gemm_bt<0><<<dim3(4, 32), 256, 0, stream>>>(lat, WvT, bv, vb, M, 512, 512, 1.0f);

  // V -> V^T per batch ([2048][512] -> [512][2048])
  transpose_to_bf16<unsigned short><<<dim3(16, 64, 2), 256, 0, stream>>>(vb, vtb, 2048, 512);

  attn_kernel<<<dim3(32, 16, 2), 256, 0, stream>>>(qb, kb, vtb, ctx);

  gemm_bt<1><<<dim3(16, 32), 256, 0, stream>>>(ctx, WoT, bo, out, M, 2048, 2048, 1.0f);
}

// Round 3
// 300.035 us; speedup vs baseline: 2.2241x; 2.2241x over previous
//
#include <hip/hip_runtime.h>
#include <stdint.h>

// GroupedQueryLatentAttention on MI355X (gfx950).
// B=2 S=2048 HID=2048 HEADS=16 D=128 GROUPS=4 LATENT=512 KV=512.
// R1/R2: attention rebuilt: QBLK=32/wave, KVBLK=64, K/V double-buffered in LDS
// (fragment-packed, conflict-free linear ds_read_b128), defer-max softmax.
// R2 fix: pack2bf via scalar RNE bf16 converts (no __hip_bfloat162 bit_cast).

#define DEV static __device__ __forceinline__

using short8 = __attribute__((ext_vector_type(8))) short;
using f32x4  = __attribute__((ext_vector_type(4))) float;

typedef __attribute__((address_space(1))) void gvoid;
typedef __attribute__((address_space(3))) void lvoid;

DEV unsigned short f2b(float f) {
  unsigned u = __builtin_bit_cast(unsigned, f);
  unsigned r = (u + 0x7fffu + ((u >> 16) & 1u)) >> 16;
  return (unsigned short)r;
}
DEV float b2f(unsigned short s) {
  unsigned u = ((unsigned)s) << 16;
  return __builtin_bit_cast(float, u);
}
DEV float as_f32(float v) { return v; }
DEV float as_f32(unsigned short v) { return b2f(v); }

DEV unsigned pack2bf(float lo, float hi) {
  return (unsigned)f2b(lo) | ((unsigned)f2b(hi) << 16);
}

// async global->LDS, 16B per lane. LDS dest resolves to firstlane base + lane*16.
DEV void async16(const void* g, void* l) {
  __builtin_amdgcn_global_load_lds((gvoid*)(uintptr_t)g,
                                   (lvoid*)(uint32_t)(uintptr_t)l, 16, 0, 0);
}

// ---------------- elementwise fp32 -> bf16 ----------------
__global__ __launch_bounds__(256) void cvt_f32_bf16(
    const float* __restrict__ in, unsigned short* __restrict__ out, long n) {
  long i = ((long)blockIdx.x * 256 + threadIdx.x) * 8;
  if (i >= n) return;
  float4 a = *(const float4*)(in + i);
  float4 b = *(const float4*)(in + i + 4);
  short8 o;
  o[0] = (short)f2b(a.x); o[1] = (short)f2b(a.y);
  o[2] = (short)f2b(a.z); o[3] = (short)f2b(a.w);
  o[4] = (short)f2b(b.x); o[5] = (short)f2b(b.y);
  o[6] = (short)f2b(b.z); o[7] = (short)f2b(b.w);
  *(short8*)(out + i) = o;
}

// ---------------- transpose [R][C] -> [C][R], out bf16 ----------------
template <typename TIN>
__global__ __launch_bounds__(256) void transpose_to_bf16(
    const TIN* __restrict__ in, unsigned short* __restrict__ out, int R, int C) {
  __shared__ float tile[32][33];
  size_t batch = (size_t)blockIdx.z * (size_t)R * C;
  int bc = blockIdx.x * 32, br = blockIdx.y * 32;
  int tx = threadIdx.x & 31, ty0 = threadIdx.x >> 5;
#pragma unroll
  for (int ty = ty0; ty < 32; ty += 8)
    tile[ty][tx] = as_f32(in[batch + (size_t)(br + ty) * C + bc + tx]);
  __syncthreads();
#pragma unroll
  for (int ty = ty0; ty < 32; ty += 8)
    out[batch + (size_t)(bc + ty) * R + br + tx] = f2b(tile[tx][ty]);
}

// ---------------- GEMM: C[M,N] = A[M,K] * Bt[N,K]^T + bias, (opt) *scale ----
template <int OUT_F32>
__global__ __launch_bounds__(256) void gemm_bt(
    const unsigned short* __restrict__ A, const unsigned short* __restrict__ Bt,
    const float* __restrict__ bias, void* __restrict__ Cout,
    int M, int N, int K, float scale) {
  __shared__ unsigned short As[128 * 32];
  __shared__ unsigned short Bs[128 * 32];
  int tid = threadIdx.x;
  int lane = tid & 63, wave = tid >> 6;
  int wr = wave >> 1, wc = wave & 1;
  int lq = lane & 15, grp = lane >> 4;
  int brow = blockIdx.y * 128, bcol = blockIdx.x * 128;

  f32x4 acc[4][4] = {};

  for (int k0 = 0; k0 < K; k0 += 32) {
    {
      int e0 = tid * 8;
      int r0 = e0 >> 5, c0 = e0 & 31;
      async16(A + (size_t)(brow + r0) * K + k0 + c0, As + e0);
      async16(Bt + (size_t)(bcol + r0) * K + k0 + c0, Bs + e0);
      int e1 = (256 + tid) * 8;
      int r1 = e1 >> 5, c1 = e1 & 31;
      async16(A + (size_t)(brow + r1) * K + k0 + c1, As + e1);
      async16(Bt + (size_t)(bcol + r1) * K + k0 + c1, Bs + e1);
    }
    __syncthreads();

    short8 af[4], bf[4];
#pragma unroll
    for (int m = 0; m < 4; m++)
      af[m] = *(const short8*)(As + (wr * 64 + m * 16 + lq) * 32 + grp * 8);
#pragma unroll
    for (int n = 0; n < 4; n++)
      bf[n] = *(const short8*)(Bs + (wc * 64 + n * 16 + lq) * 32 + grp * 8);
#pragma unroll
    for (int m = 0; m < 4; m++)
#pragma unroll
      for (int n = 0; n < 4; n++)
        acc[m][n] = __builtin_amdgcn_mfma_f32_16x16x32_bf16(af[m], bf[n], acc[m][n], 0, 0, 0);
    __syncthreads();
  }

#pragma unroll
  for (int n = 0; n < 4; n++) {
    int col = bcol + wc * 64 + n * 16 + lq;
    float bv = bias[col];
#pragma unroll
    for (int m = 0; m < 4; m++) {
#pragma unroll
      for (int r = 0; r < 4; r++) {
        int row = brow + wr * 64 + m * 16 + grp * 4 + r;
        float v = (acc[m][n][r] + bv) * scale;
        if (OUT_F32)
          ((float*)Cout)[(size_t)row * N + col] = v;
        else
          ((unsigned short*)Cout)[(size_t)row * N + col] = f2b(v);
      }
    }
  }
}

// ---------------- flash attention (R1) ----------------
// grid (S/128, HEADS, B), block 256 = 4 waves; each wave owns 32 q-rows
// (2 sub-tiles of 16). KVBLK=64. K/V staged in LDS, fragment-packed
// ([frag][lane][16B]) so all ds_read_b128 are linear-in-lane (0 conflicts).
// Double-buffered; one barrier per KV tile. Swapped QK^T keeps softmax
// in-lane; defer-max (THR=8) skips shuffles+rescale on most tiles.
__global__ __launch_bounds__(256, 2) void attn_kernel(
    const unsigned short* __restrict__ q,   // [B*S][2048], pre-scaled
    const unsigned short* __restrict__ k,   // [B*S][512]
    const unsigned short* __restrict__ vt,  // [(b*4+g)*128 + d][2048]
    unsigned short* __restrict__ ctx) {     // [B*S][2048]
  // KV[buf][frag 0..31][512 elems]; frags 0..15 = K (fi = t*4+c), 16..31 = V (d0*2+u)
  __shared__ unsigned short KV[2][32][512];
  const int lane = threadIdx.x & 63, wave = threadIdx.x >> 6;
  const int lq = lane & 15, grp = lane >> 4;
  const int h = blockIdx.y, b = blockIdx.z, g = h >> 2;
  const int qbase = blockIdx.x * 128 + wave * 32;

  short8 qf[2][4];
#pragma unroll
  for (int qs = 0; qs < 2; qs++) {
    const unsigned short* qp =
        q + ((size_t)(b * 2048 + qbase + qs * 16 + lq)) * 2048 + h * 128 + grp * 8;
#pragma unroll
    for (int c = 0; c < 4; c++) qf[qs][c] = *(const short8*)(qp + c * 32);
  }

  f32x4 o[2][8] = {};
  float mrun[2] = {-3.0e38f, -3.0e38f};
  float lsum[2] = {0.f, 0.f};

  const int kvperm = (lq >> 2) * 8 + (lq & 3);  // MFMA A-row -> kv offset map
  const unsigned short* kB = k + (size_t)b * 2048 * 512 + g * 128 + grp * 8;
  const unsigned short* vB =
      vt + ((size_t)((b * 4 + g) * 128 + lq)) * 2048 + grp * 8;
  const int fbase = wave * 8;  // each wave stages 8 of the 32 fragments
  unsigned short* dstb = &KV[0][fbase][0] + lane * 8;

  auto stage = [&](int bn, int kv0) {
    unsigned short* dst = dstb + bn * 16384;
    if (fbase < 16) {  // K fragments: row = kv0 + (t>>1)*32 + (t&1)*4 + perm(lq)
#pragma unroll
      for (int j = 0; j < 8; j++) {
        int f = fbase + j, t = f >> 2, c = f & 3;
        const unsigned short* src =
            kB + (size_t)(kv0 + (t >> 1) * 32 + (t & 1) * 4 + kvperm) * 512 + c * 32;
        async16(src, dst + j * 512);
      }
    } else {  // V fragments: row = d0*16 + lq, col = kv0 + u*32 + grp*8
#pragma unroll
      for (int j = 0; j < 8; j++) {
        int f = fbase - 16 + j, d0 = f >> 1, u = f & 1;
        const unsigned short* src = vB + (size_t)(d0 * 16) * 2048 + kv0 + u * 32;
        async16(src, dst + j * 512);
      }
    }
  };

  stage(0, 0);
  int buf = 0;
  for (int it = 0; it < 32; ++it) {
    __syncthreads();  // drains staging vmcnt; all waves done reading other buf
    if (it < 31) stage(buf ^ 1, (it + 1) * 64);
    const unsigned short* Kb = &KV[buf][0][0] + lane * 8;

    // QK^T: s[qs][t][i] = score(qrow=lq of set qs, kv = (t>>1)*32+(t&1)*4+grp*8+i)
    f32x4 s[2][4] = {};
#pragma unroll
    for (int c = 0; c < 4; c++) {
      short8 kf0 = *(const short8*)(Kb + (0 + c) * 512);
      short8 kf1 = *(const short8*)(Kb + (4 + c) * 512);
      short8 kf2 = *(const short8*)(Kb + (8 + c) * 512);
      short8 kf3 = *(const short8*)(Kb + (12 + c) * 512);
#pragma unroll
      for (int qs = 0; qs < 2; qs++) {
        s[qs][0] = __builtin_amdgcn_mfma_f32_16x16x32_bf16(kf0, qf[qs][c], s[qs][0], 0, 0, 0);
        s[qs][1] = __builtin_amdgcn_mfma_f32_16x16x32_bf16(kf1, qf[qs][c], s[qs][1], 0, 0, 0);
        s[qs][2] = __builtin_amdgcn_mfma_f32_16x16x32_bf16(kf2, qf[qs][c], s[qs][2], 0, 0, 0);
        s[qs][3] = __builtin_amdgcn_mfma_f32_16x16x32_bf16(kf3, qf[qs][c], s[qs][3], 0, 0, 0);
      }
    }

    // defer-max online softmax
    float lm[2];
#pragma unroll
    for (int qs = 0; qs < 2; qs++) {
      float a = fmaxf(fmaxf(s[qs][0][0], s[qs][0][1]), fmaxf(s[qs][0][2], s[qs][0][3]));
      float bm = fmaxf(fmaxf(s[qs][1][0], s[qs][1][1]), fmaxf(s[qs][1][2], s[qs][1][3]));
      float cm = fmaxf(fmaxf(s[qs][2][0], s[qs][2][1]), fmaxf(s[qs][2][2], s[qs][2][3]));
      float dm = fmaxf(fmaxf(s[qs][3][0], s[qs][3][1]), fmaxf(s[qs][3][2], s[qs][3][3]));
      lm[qs] = fmaxf(fmaxf(a, bm), fmaxf(cm, dm));
    }
    if (__any((lm[0] > mrun[0] + 8.f) || (lm[1] > mrun[1] + 8.f))) {
#pragma unroll
      for (int qs = 0; qs < 2; qs++) {
        float t0 = fmaxf(lm[qs], __shfl_xor(lm[qs], 16));
        t0 = fmaxf(t0, __shfl_xor(t0, 32));
        float mnew = fmaxf(mrun[qs], t0);
        float al = __expf(mrun[qs] - mnew);
        lsum[qs] *= al;
        mrun[qs] = mnew;
        float a0 = __shfl(al, grp * 4 + 0), a1 = __shfl(al, grp * 4 + 1);
        float a2 = __shfl(al, grp * 4 + 2), a3 = __shfl(al, grp * 4 + 3);
#pragma unroll
        for (int d0 = 0; d0 < 8; d0++) {
          o[qs][d0][0] *= a0; o[qs][d0][1] *= a1;
          o[qs][d0][2] *= a2; o[qs][d0][3] *= a3;
        }
      }
    }

    short8 pf[2][2];
#pragma unroll
    for (int qs = 0; qs < 2; qs++) {
      float m = mrun[qs], ps = 0.f;
      union { short8 v; unsigned w[4]; } pk0, pk1;
#pragma unroll
      for (int t = 0; t < 4; t++) {
        float e0 = __expf(s[qs][t][0] - m);
        float e1 = __expf(s[qs][t][1] - m);
        float e2 = __expf(s[qs][t][2] - m);
        float e3 = __expf(s[qs][t][3] - m);
        ps += (e0 + e1) + (e2 + e3);
        unsigned w0 = pack2bf(e0, e1), w1 = pack2bf(e2, e3);
        if (t == 0) { pk0.w[0] = w0; pk0.w[1] = w1; }
        else if (t == 1) { pk0.w[2] = w0; pk0.w[3] = w1; }
        else if (t == 2) { pk1.w[0] = w0; pk1.w[1] = w1; }
        else { pk1.w[2] = w0; pk1.w[3] = w1; }
      }
      lsum[qs] += ps;
      pf[qs][0] = pk0.v;
      pf[qs][1] = pk1.v;
    }

    // PV: o[qs][d0] += P[qs][kv 0..31]*V + P[qs][kv 32..63]*V
    const unsigned short* Vb = Kb + 16 * 512;
#pragma unroll
    for (int d0 = 0; d0 < 8; d0++) {
      short8 v0 = *(const short8*)(Vb + (d0 * 2 + 0) * 512);
      short8 v1 = *(const short8*)(Vb + (d0 * 2 + 1) * 512);
#pragma unroll
      for (int qs = 0; qs < 2; qs++) {
        o[qs][d0] = __builtin_amdgcn_mfma_f32_16x16x32_bf16(pf[qs][0], v0, o[qs][d0], 0, 0, 0);
        o[qs][d0] = __builtin_amdgcn_mfma_f32_16x16x32_bf16(pf[qs][1], v1, o[qs][d0], 0, 0, 0);
      }
    }
    buf ^= 1;
  }

  unsigned short* cp = ctx + ((size_t)(b * 2048 + qbase)) * 2048 + h * 128;
#pragma unroll
  for (int qs = 0; qs < 2; qs++) {
    float l = lsum[qs];
    l += __shfl_xor(l, 16);
    l += __shfl_xor(l, 32);
    float ri = 1.0f / l;
    float r0 = __shfl(ri, grp * 4 + 0), r1 = __shfl(ri, grp * 4 + 1);
    float r2 = __shfl(ri, grp * 4 + 2), r3 = __shfl(ri, grp * 4 + 3);
#pragma unroll
    for (int d0 = 0; d0 < 8; d0++) {
      int col = d0 * 16 + lq;
      cp[(size_t)(qs * 16 + grp * 4 + 0) * 2048 + col] = f2b(o[qs][d0][0] * r0);
      cp[(size_t)(qs * 16 + grp * 4 + 1) * 2048 + col] = f2b(o[qs][d0][1] * r1);
      cp[(size_t)(qs * 16 + grp * 4 + 2) * 2048 + col] = f2b(o[qs][d0][2] * r2);
      cp[(size_t)(qs * 16 + grp * 4 + 3) * 2048 + col] = f2b(o[qs][d0][3] * r3);
    }
  }
}

// ---------------- host ----------------
extern "C" void kernel_launch(void* const* d_in, const int* in_sizes, int n_in,
                              void* d_out, int out_size, void* d_ws, size_t ws_size,
                              hipStream_t stream) {
  const float* h  = (const float*)d_in[0];
  const float* Wq = (const float*)d_in[1];
  const float* bq = (const float*)d_in[2];
  const float* Wl = (const float*)d_in[3];
  const float* bl = (const float*)d_in[4];
  const float* Wk = (const float*)d_in[5];
  const float* bk = (const float*)d_in[6];
  const float* Wv = (const float*)d_in[7];
  const float* bv = (const float*)d_in[8];
  const float* Wo = (const float*)d_in[9];
  const float* bo = (const float*)d_in[10];
  float* out = (float*)d_out;

  const int M = 4096;  // B*S

  char* w = (char*)d_ws;
  auto take = [&](size_t elems) {
    void* p = (void*)w;
    w += (elems * 2 + 255) & ~(size_t)255;
    return (unsigned short*)p;
  };
  unsigned short* hb  = take(8388608);  // [4096][2048]
  unsigned short* WqT = take(4194304);  // [2048][2048]
  unsigned short* WlT = take(1048576);  // [512][2048]
  unsigned short* WkT = take(262144);   // [512][512]
  unsigned short* WvT = take(262144);   // [512][512]
  unsigned short* WoT = take(4194304);  // [2048][2048]
  unsigned short* qb  = take(8388608);  // [4096][2048]
  unsigned short* lat = take(2097152);  // [4096][512]
  unsigned short* kb  = take(2097152);  // [4096][512]
  unsigned short* vb  = take(2097152);  // [4096][512]
  unsigned short* vtb = take(2097152);  // [2*512][2048]
  unsigned short* ctx = take(8388608);  // [4096][2048]

  cvt_f32_bf16<<<4096, 256, 0, stream>>>(h, hb, 8388608L);
  transpose_to_bf16<float><<<dim3(64, 64, 1), 256, 0, stream>>>(Wq, WqT, 2048, 2048);
  transpose_to_bf16<float><<<dim3(16, 64, 1), 256, 0, stream>>>(Wl, WlT, 2048, 512);
  transpose_to_bf16<float><<<dim3(16, 16, 1), 256, 0, stream>>>(Wk, WkT, 512, 512);
  transpose_to_bf16<float><<<dim3(16, 16, 1), 256, 0, stream>>>(Wv, WvT, 512, 512);
  transpose_to_bf16<float><<<dim3(64, 64, 1), 256, 0, stream>>>(Wo, WoT, 2048, 2048);

  const float scale = 0.08838834764831845f;  // 1/sqrt(128), folded into q
  gemm_bt<0><<<dim3(16, 32), 256, 0, stream>>>(hb, WqT, bq, qb, M, 2048, 2048, scale);
  gemm_bt<0><<<dim3(4, 32), 256, 0, stream>>>(hb, WlT, bl, lat, M, 512, 2048, 1.0f);
  gemm_bt<0><<<dim3(4, 32), 256, 0, stream>>>(lat, WkT, bk, kb, M, 512, 512, 1.0f);
  gemm_bt<0><<<dim3(4, 32), 256, 0, stream>>>(lat, WvT, bv, vb, M, 512, 512, 1.0f);

  transpose_to_bf16<unsigned short><<<dim3(16, 64, 2), 256, 0, stream>>>(vb, vtb, 2048, 512);

  attn_kernel<<<dim3(16, 16, 2), 256, 0, stream>>>(qb, kb, vtb, ctx);

  gemm_bt<1><<<dim3(16, 32), 256, 0, stream>>>(ctx, WoT, bo, out, M, 2048, 2048, 1.0f);
}

// Round 4
// 283.484 us; speedup vs baseline: 2.3540x; 1.0584x over previous
//
#include <hip/hip_runtime.h>
#include <stdint.h>

// GroupedQueryLatentAttention on MI355X (gfx950).
// B=2 S=2048 HID=2048 HEADS=16 D=128 GROUPS=4 LATENT=512 KV=512.
// R4: big GEMMs (q-proj, o-proj) moved to a 256x128x64 phase-interleaved
// kernel: counted vmcnt (never 0 in main loop), raw s_barrier, st_16x32
// LDS swizzle on both stage-source and ds_read, setprio around MFMA.

#define DEV static __device__ __forceinline__

using short8 = __attribute__((ext_vector_type(8))) short;
using f32x4  = __attribute__((ext_vector_type(4))) float;

typedef __attribute__((address_space(1))) void gvoid;
typedef __attribute__((address_space(3))) void lvoid;

DEV unsigned short f2b(float f) {
  unsigned u = __builtin_bit_cast(unsigned, f);
  unsigned r = (u + 0x7fffu + ((u >> 16) & 1u)) >> 16;
  return (unsigned short)r;
}
DEV float b2f(unsigned short s) {
  unsigned u = ((unsigned)s) << 16;
  return __builtin_bit_cast(float, u);
}
DEV float as_f32(float v) { return v; }
DEV float as_f32(unsigned short v) { return b2f(v); }

DEV unsigned pack2bf(float lo, float hi) {
  return (unsigned)f2b(lo) | ((unsigned)f2b(hi) << 16);
}

// async global->LDS, 16B per lane. LDS dest resolves to firstlane base + lane*16.
DEV void async16(const void* g, void* l) {
  __builtin_amdgcn_global_load_lds((gvoid*)(uintptr_t)g,
                                   (lvoid*)(uint32_t)(uintptr_t)l, 16, 0, 0);
}

DEV f32x4 mfma16(short8 a, short8 b, f32x4 c) {
  return __builtin_amdgcn_mfma_f32_16x16x32_bf16(a, b, c, 0, 0, 0);
}

// ---------------- elementwise fp32 -> bf16 ----------------
__global__ __launch_bounds__(256) void cvt_f32_bf16(
    const float* __restrict__ in, unsigned short* __restrict__ out, long n) {
  long i = ((long)blockIdx.x * 256 + threadIdx.x) * 8;
  if (i >= n) return;
  float4 a = *(const float4*)(in + i);
  float4 b = *(const float4*)(in + i + 4);
  short8 o;
  o[0] = (short)f2b(a.x); o[1] = (short)f2b(a.y);
  o[2] = (short)f2b(a.z); o[3] = (short)f2b(a.w);
  o[4] = (short)f2b(b.x); o[5] = (short)f2b(b.y);
  o[6] = (short)f2b(b.z); o[7] = (short)f2b(b.w);
  *(short8*)(out + i) = o;
}

// ---------------- transpose [R][C] -> [C][R], out bf16 ----------------
template <typename TIN>
__global__ __launch_bounds__(256) void transpose_to_bf16(
    const TIN* __restrict__ in, unsigned short* __restrict__ out, int R, int C) {
  __shared__ float tile[32][33];
  size_t batch = (size_t)blockIdx.z * (size_t)R * C;
  int bc = blockIdx.x * 32, br = blockIdx.y * 32;
  int tx = threadIdx.x & 31, ty0 = threadIdx.x >> 5;
#pragma unroll
  for (int ty = ty0; ty < 32; ty += 8)
    tile[ty][tx] = as_f32(in[batch + (size_t)(br + ty) * C + bc + tx]);
  __syncthreads();
#pragma unroll
  for (int ty = ty0; ty < 32; ty += 8)
    out[batch + (size_t)(bc + ty) * R + br + tx] = f2b(tile[tx][ty]);
}

// ---------------- GEMM 128x128 (small N): C = A * Bt^T + bias ----------------
template <int OUT_F32>
__global__ __launch_bounds__(256) void gemm_bt(
    const unsigned short* __restrict__ A, const unsigned short* __restrict__ Bt,
    const float* __restrict__ bias, void* __restrict__ Cout,
    int M, int N, int K, float scale) {
  __shared__ unsigned short As[128 * 32];
  __shared__ unsigned short Bs[128 * 32];
  int tid = threadIdx.x;
  int lane = tid & 63, wave = tid >> 6;
  int wr = wave >> 1, wc = wave & 1;
  int lq = lane & 15, grp = lane >> 4;
  int brow = blockIdx.y * 128, bcol = blockIdx.x * 128;

  f32x4 acc[4][4] = {};

  for (int k0 = 0; k0 < K; k0 += 32) {
    {
      int e0 = tid * 8;
      int r0 = e0 >> 5, c0 = e0 & 31;
      async16(A + (size_t)(brow + r0) * K + k0 + c0, As + e0);
      async16(Bt + (size_t)(bcol + r0) * K + k0 + c0, Bs + e0);
      int e1 = (256 + tid) * 8;
      int r1 = e1 >> 5, c1 = e1 & 31;
      async16(A + (size_t)(brow + r1) * K + k0 + c1, As + e1);
      async16(Bt + (size_t)(bcol + r1) * K + k0 + c1, Bs + e1);
    }
    __syncthreads();

    short8 af[4], bf[4];
#pragma unroll
    for (int m = 0; m < 4; m++)
      af[m] = *(const short8*)(As + (wr * 64 + m * 16 + lq) * 32 + grp * 8);
#pragma unroll
    for (int n = 0; n < 4; n++)
      bf[n] = *(const short8*)(Bs + (wc * 64 + n * 16 + lq) * 32 + grp * 8);
#pragma unroll
    for (int m = 0; m < 4; m++)
#pragma unroll
      for (int n = 0; n < 4; n++)
        acc[m][n] = mfma16(af[m], bf[n], acc[m][n]);
    __syncthreads();
  }

#pragma unroll
  for (int n = 0; n < 4; n++) {
    int col = bcol + wc * 64 + n * 16 + lq;
    float bv = bias[col];
#pragma unroll
    for (int m = 0; m < 4; m++) {
#pragma unroll
      for (int r = 0; r < 4; r++) {
        int row = brow + wr * 64 + m * 16 + grp * 4 + r;
        float v = (acc[m][n][r] + bv) * scale;
        if (OUT_F32)
          ((float*)Cout)[(size_t)row * N + col] = v;
        else
          ((unsigned short*)Cout)[(size_t)row * N + col] = f2b(v);
      }
    }
  }
}

// ---------------- GEMM 256x128x64, 8 waves, phase-interleaved ----------------
// Waves: wr = wave>>1 (0..3, 64-row band), wc = wave&1 (0..1, 64-col band).
// LDS: As [2][256][64], Bs [2][128][64] bf16, st_16x32 swizzle
// (byte ^= ((byte>>9)&1)<<5), applied to ds_read addr AND stage source.
// Per K-tile (BK=64): 2 phases x 16 MFMA. Counted vmcnt: per-wave stage order
// [A0,A1,A2 | A3,B-P0,B-P1]; B-P1 (needed only in phase 1) rides across the
// tile boundary -> vmcnt(1) at boundary, vmcnt(6) mid-tile, never 0 in loop.
template <int OUT_F32>
__global__ __launch_bounds__(512, 2) void gemm_bt_256(
    const unsigned short* __restrict__ A, const unsigned short* __restrict__ Bt,
    const float* __restrict__ bias, void* __restrict__ Cout,
    int M, int N, int K, float scale) {
  __shared__ __align__(1024) unsigned short As[2][16384];
  __shared__ __align__(1024) unsigned short Bs[2][8192];
  const int tid = threadIdx.x;
  const int lane = tid & 63, wave = tid >> 6;
  const int wr = wave >> 1, wc = wave & 1;
  const int lq = lane & 15, grp = lane >> 4;

  // XCD-aware swizzle (nwg % 8 == 0 for our shapes)
  const int gx = gridDim.x;
  int nwg = gx * gridDim.y;
  int bid = blockIdx.y * gx + blockIdx.x;
  int wgid = (bid & 7) * (nwg >> 3) + (bid >> 3);
  int bx = wgid % gx, by = wgid / gx;
  const int brow = by * 256, bcol = bx * 128;

  // ---- staging slots (per-wave): 4 A slots + 2 B slots, 1KB each ----
  // dest byte (buffer-relative, linear); source = sigma(dest) logical elem.
#define MKSLOT(db, mat, rb)                                            \
  ({ int d_ = (db) + lane * 16;                                        \
     int L_ = d_ ^ (((d_ >> 9) & 1) << 5);                             \
     (mat) + (size_t)((rb) + (L_ >> 7)) * K + ((L_ & 127) >> 1); })
  const int dbA0 = wave * 1024, dbA1 = dbA0 + 8192, dbA2 = dbA0 + 16384,
            dbA3 = dbA0 + 24576;
  const int dbB0 = (wave < 4) ? wave * 1024 : 8192 + (wave - 4) * 1024;
  const int dbB1 = dbB0 + 4096;
  const unsigned short* srcA0 = MKSLOT(dbA0, A, brow);
  const unsigned short* srcA1 = MKSLOT(dbA1, A, brow);
  const unsigned short* srcA2 = MKSLOT(dbA2, A, brow);
  const unsigned short* srcA3 = MKSLOT(dbA3, A, brow);
  const unsigned short* srcB0 = MKSLOT(dbB0, Bt, bcol);
  const unsigned short* srcB1 = MKSLOT(dbB1, Bt, bcol);
  char* dstA0 = (char*)&As[0][0] + dbA0 + lane * 16;
  char* dstA1 = (char*)&As[0][0] + dbA1 + lane * 16;
  char* dstA2 = (char*)&As[0][0] + dbA2 + lane * 16;
  char* dstA3 = (char*)&As[0][0] + dbA3 + lane * 16;
  char* dstB0 = (char*)&Bs[0][0] + dbB0 + lane * 16;
  char* dstB1 = (char*)&Bs[0][0] + dbB1 + lane * 16;
#define STA(i, b, k0) async16(srcA##i + (k0), dstA##i + (b) * 32768)
#define STB(i, b, k0) async16(srcB##i + (k0), dstB##i + (b) * 16384)

  // swizzled ds_read of one 16B fragment: row includes lq; kk in {0,1}
  auto ldA = [&](int cur, int row, int kk) -> short8 {
    int p = row * 128 + kk * 64 + grp * 16;
    p ^= ((p >> 9) & 1) << 5;
    return *(const short8*)((const char*)&As[cur][0] + p);
  };
  auto ldB = [&](int cur, int row, int kk) -> short8 {
    int p = row * 128 + kk * 64 + grp * 16;
    p ^= ((p >> 9) & 1) << 5;
    return *(const short8*)((const char*)&Bs[cur][0] + p);
  };

  f32x4 acc[4][4] = {};
  short8 af[4][2], bf[4][2];
  const int NT = K >> 6;

  // prologue: stage tile 0 into buf 0; keep B-P1 in flight (steady state)
  STA(0, 0, 0); STA(1, 0, 0); STA(2, 0, 0); STA(3, 0, 0);
  STB(0, 0, 0); STB(1, 0, 0);
  asm volatile("s_waitcnt vmcnt(1)" ::: "memory");
  __builtin_amdgcn_s_barrier();

  for (int t = 0; t < NT; ++t) {
    const int cur = t & 1, nb = cur ^ 1;
    const bool pf = (t + 1 < NT);
    const int k0n = (t + 1) << 6;

    // ---- phase 0: cols n0-1 ----
#pragma unroll
    for (int m = 0; m < 4; m++) {
      af[m][0] = ldA(cur, wr * 64 + m * 16 + lq, 0);
      af[m][1] = ldA(cur, wr * 64 + m * 16 + lq, 1);
    }
#pragma unroll
    for (int n = 0; n < 2; n++) {
      bf[n][0] = ldB(cur, wc * 64 + n * 16 + lq, 0);
      bf[n][1] = ldB(cur, wc * 64 + n * 16 + lq, 1);
    }
    if (pf) { STA(0, nb, k0n); STA(1, nb, k0n); STA(2, nb, k0n); }
    __builtin_amdgcn_s_barrier();
    __builtin_amdgcn_s_setprio(1);
#pragma unroll
    for (int m = 0; m < 4; m++)
#pragma unroll
      for (int n = 0; n < 2; n++) {
        acc[m][n] = mfma16(af[m][0], bf[n][0], acc[m][n]);
        acc[m][n] = mfma16(af[m][1], bf[n][1], acc[m][n]);
      }
    __builtin_amdgcn_s_setprio(0);
    __builtin_amdgcn_s_barrier();

    // ---- phase 1: cols n2-3 ----
    if (pf) {
      STA(3, nb, k0n); STB(0, nb, k0n); STB(1, nb, k0n);
      // outstanding: t B-P1 (1) + 6 just-staged -> drain the oldest 1
      asm volatile("s_waitcnt vmcnt(6)" ::: "memory");
    } else {
      asm volatile("s_waitcnt vmcnt(0)" ::: "memory");
    }
    __builtin_amdgcn_s_barrier();
#pragma unroll
    for (int n = 0; n < 2; n++) {
      bf[2 + n][0] = ldB(cur, wc * 64 + (2 + n) * 16 + lq, 0);
      bf[2 + n][1] = ldB(cur, wc * 64 + (2 + n) * 16 + lq, 1);
    }
    __builtin_amdgcn_s_setprio(1);
#pragma unroll
    for (int m = 0; m < 4; m++)
#pragma unroll
      for (int n = 2; n < 4; n++) {
        acc[m][n] = mfma16(af[m][0], bf[n][0], acc[m][n]);
        acc[m][n] = mfma16(af[m][1], bf[n][1], acc[m][n]);
      }
    __builtin_amdgcn_s_setprio(0);
    if (pf) {
      // next tile's P0 needs A(4) + B-P0 landed; keep B-P1 (last) in flight
      asm volatile("s_waitcnt vmcnt(1)" ::: "memory");
    }
    __builtin_amdgcn_s_barrier();
  }

  // ---- epilogue ----
#pragma unroll
  for (int n = 0; n < 4; n++) {
    int col = bcol + wc * 64 + n * 16 + lq;
    float bv = bias[col];
#pragma unroll
    for (int m = 0; m < 4; m++) {
#pragma unroll
      for (int r = 0; r < 4; r++) {
        int row = brow + wr * 64 + m * 16 + grp * 4 + r;
        float v = (acc[m][n][r] + bv) * scale;
        if (OUT_F32)
          ((float*)Cout)[(size_t)row * N + col] = v;
        else
          ((unsigned short*)Cout)[(size_t)row * N + col] = f2b(v);
      }
    }
  }
#undef STA
#undef STB
#undef MKSLOT
}

// ---------------- flash attention (unchanged from R3) ----------------
__global__ __launch_bounds__(256, 2) void attn_kernel(
    const unsigned short* __restrict__ q,   // [B*S][2048], pre-scaled
    const unsigned short* __restrict__ k,   // [B*S][512]
    const unsigned short* __restrict__ vt,  // [(b*4+g)*128 + d][2048]
    unsigned short* __restrict__ ctx) {     // [B*S][2048]
  __shared__ unsigned short KV[2][32][512];
  const int lane = threadIdx.x & 63, wave = threadIdx.x >> 6;
  const int lq = lane & 15, grp = lane >> 4;
  const int h = blockIdx.y, b = blockIdx.z, g = h >> 2;
  const int qbase = blockIdx.x * 128 + wave * 32;

  short8 qf[2][4];
#pragma unroll
  for (int qs = 0; qs < 2; qs++) {
    const unsigned short* qp =
        q + ((size_t)(b * 2048 + qbase + qs * 16 + lq)) * 2048 + h * 128 + grp * 8;
#pragma unroll
    for (int c = 0; c < 4; c++) qf[qs][c] = *(const short8*)(qp + c * 32);
  }

  f32x4 o[2][8] = {};
  float mrun[2] = {-3.0e38f, -3.0e38f};
  float lsum[2] = {0.f, 0.f};

  const int kvperm = (lq >> 2) * 8 + (lq & 3);
  const unsigned short* kB = k + (size_t)b * 2048 * 512 + g * 128 + grp * 8;
  const unsigned short* vB =
      vt + ((size_t)((b * 4 + g) * 128 + lq)) * 2048 + grp * 8;
  const int fbase = wave * 8;
  unsigned short* dstb = &KV[0][fbase][0] + lane * 8;

  auto stage = [&](int bn, int kv0) {
    unsigned short* dst = dstb + bn * 16384;
    if (fbase < 16) {
#pragma unroll
      for (int j = 0; j < 8; j++) {
        int f = fbase + j, t = f >> 2, c = f & 3;
        const unsigned short* src =
            kB + (size_t)(kv0 + (t >> 1) * 32 + (t & 1) * 4 + kvperm) * 512 + c * 32;
        async16(src, dst + j * 512);
      }
    } else {
#pragma unroll
      for (int j = 0; j < 8; j++) {
        int f = fbase - 16 + j, d0 = f >> 1, u = f & 1;
        const unsigned short* src = vB + (size_t)(d0 * 16) * 2048 + kv0 + u * 32;
        async16(src, dst + j * 512);
      }
    }
  };

  stage(0, 0);
  int buf = 0;
  for (int it = 0; it < 32; ++it) {
    __syncthreads();
    if (it < 31) stage(buf ^ 1, (it + 1) * 64);
    const unsigned short* Kb = &KV[buf][0][0] + lane * 8;

    f32x4 s[2][4] = {};
#pragma unroll
    for (int c = 0; c < 4; c++) {
      short8 kf0 = *(const short8*)(Kb + (0 + c) * 512);
      short8 kf1 = *(const short8*)(Kb + (4 + c) * 512);
      short8 kf2 = *(const short8*)(Kb + (8 + c) * 512);
      short8 kf3 = *(const short8*)(Kb + (12 + c) * 512);
#pragma unroll
      for (int qs = 0; qs < 2; qs++) {
        s[qs][0] = mfma16(kf0, qf[qs][c], s[qs][0]);
        s[qs][1] = mfma16(kf1, qf[qs][c], s[qs][1]);
        s[qs][2] = mfma16(kf2, qf[qs][c], s[qs][2]);
        s[qs][3] = mfma16(kf3, qf[qs][c], s[qs][3]);
      }
    }

    float lm[2];
#pragma unroll
    for (int qs = 0; qs < 2; qs++) {
      float a = fmaxf(fmaxf(s[qs][0][0], s[qs][0][1]), fmaxf(s[qs][0][2], s[qs][0][3]));
      float bm = fmaxf(fmaxf(s[qs][1][0], s[qs][1][1]), fmaxf(s[qs][1][2], s[qs][1][3]));
      float cm = fmaxf(fmaxf(s[qs][2][0], s[qs][2][1]), fmaxf(s[qs][2][2], s[qs][2][3]));
      float dm = fmaxf(fmaxf(s[qs][3][0], s[qs][3][1]), fmaxf(s[qs][3][2], s[qs][3][3]));
      lm[qs] = fmaxf(fmaxf(a, bm), fmaxf(cm, dm));
    }
    if (__any((lm[0] > mrun[0] + 8.f) || (lm[1] > mrun[1] + 8.f))) {
#pragma unroll
      for (int qs = 0; qs < 2; qs++) {
        float t0 = fmaxf(lm[qs], __shfl_xor(lm[qs], 16));
        t0 = fmaxf(t0, __shfl_xor(t0, 32));
        float mnew = fmaxf(mrun[qs], t0);
        float al = __expf(mrun[qs] - mnew);
        lsum[qs] *= al;
        mrun[qs] = mnew;
        float a0 = __shfl(al, grp * 4 + 0), a1 = __shfl(al, grp * 4 + 1);
        float a2 = __shfl(al, grp * 4 + 2), a3 = __shfl(al, grp * 4 + 3);
#pragma unroll
        for (int d0 = 0; d0 < 8; d0++) {
          o[qs][d0][0] *= a0; o[qs][d0][1] *= a1;
          o[qs][d0][2] *= a2; o[qs][d0][3] *= a3;
        }
      }
    }

    short8 pf[2][2];
#pragma unroll
    for (int qs = 0; qs < 2; qs++) {
      float m = mrun[qs], ps = 0.f;
      union { short8 v; unsigned w[4]; } pk0, pk1;
#pragma unroll
      for (int t = 0; t < 4; t++) {
        float e0 = __expf(s[qs][t][0] - m);
        float e1 = __expf(s[qs][t][1] - m);
        float e2 = __expf(s[qs][t][2] - m);
        float e3 = __expf(s[qs][t][3] - m);
        ps += (e0 + e1) + (e2 + e3);
        unsigned w0 = pack2bf(e0, e1), w1 = pack2bf(e2, e3);
        if (t == 0) { pk0.w[0] = w0; pk0.w[1] = w1; }
        else if (t == 1) { pk0.w[2] = w0; pk0.w[3] = w1; }
        else if (t == 2) { pk1.w[0] = w0; pk1.w[1] = w1; }
        else { pk1.w[2] = w0; pk1.w[3] = w1; }
      }
      lsum[qs] += ps;
      pf[qs][0] = pk0.v;
      pf[qs][1] = pk1.v;
    }

    const unsigned short* Vb = Kb + 16 * 512;
#pragma unroll
    for (int d0 = 0; d0 < 8; d0++) {
      short8 v0 = *(const short8*)(Vb + (d0 * 2 + 0) * 512);
      short8 v1 = *(const short8*)(Vb + (d0 * 2 + 1) * 512);
#pragma unroll
      for (int qs = 0; qs < 2; qs++) {
        o[qs][d0] = mfma16(pf[qs][0], v0, o[qs][d0]);
        o[qs][d0] = mfma16(pf[qs][1], v1, o[qs][d0]);
      }
    }
    buf ^= 1;
  }

  unsigned short* cp = ctx + ((size_t)(b * 2048 + qbase)) * 2048 + h * 128;
#pragma unroll
  for (int qs = 0; qs < 2; qs++) {
    float l = lsum[qs];
    l += __shfl_xor(l, 16);
    l += __shfl_xor(l, 32);
    float ri = 1.0f / l;
    float r0 = __shfl(ri, grp * 4 + 0), r1 = __shfl(ri, grp * 4 + 1);
    float r2 = __shfl(ri, grp * 4 + 2), r3 = __shfl(ri, grp * 4 + 3);
#pragma unroll
    for (int d0 = 0; d0 < 8; d0++) {
      int col = d0 * 16 + lq;
      cp[(size_t)(qs * 16 + grp * 4 + 0) * 2048 + col] = f2b(o[qs][d0][0] * r0);
      cp[(size_t)(qs * 16 + grp * 4 + 1) * 2048 + col] = f2b(o[qs][d0][1] * r1);
      cp[(size_t)(qs * 16 + grp * 4 + 2) * 2048 + col] = f2b(o[qs][d0][2] * r2);
      cp[(size_t)(qs * 16 + grp * 4 + 3) * 2048 + col] = f2b(o[qs][d0][3] * r3);
    }
  }
}

// ---------------- host ----------------
extern "C" void kernel_launch(void* const* d_in, const int* in_sizes, int n_in,
                              void* d_out, int out_size, void* d_ws, size_t ws_size,
                              hipStream_t stream) {
  const float* h  = (const float*)d_in[0];
  const float* Wq = (const float*)d_in[1];
  const float* bq = (const float*)d_in[2];
  const float* Wl = (const float*)d_in[3];
  const float* bl = (const float*)d_in[4];
  const float* Wk = (const float*)d_in[5];
  const float* bk = (const float*)d_in[6];
  const float* Wv = (const float*)d_in[7];
  const float* bv = (const float*)d_in[8];
  const float* Wo = (const float*)d_in[9];
  const float* bo = (const float*)d_in[10];
  float* out = (float*)d_out;

  const int M = 4096;  // B*S

  char* w = (char*)d_ws;
  auto take = [&](size_t elems) {
    void* p = (void*)w;
    w += (elems * 2 + 255) & ~(size_t)255;
    return (unsigned short*)p;
  };
  unsigned short* hb  = take(8388608);  // [4096][2048]
  unsigned short* WqT = take(4194304);  // [2048][2048]
  unsigned short* WlT = take(1048576);  // [512][2048]
  unsigned short* WkT = take(262144);   // [512][512]
  unsigned short* WvT = take(262144);   // [512][512]
  unsigned short* WoT = take(4194304);  // [2048][2048]
  unsigned short* qb  = take(8388608);  // [4096][2048]
  unsigned short* lat = take(2097152);  // [4096][512]
  unsigned short* kb  = take(2097152);  // [4096][512]
  unsigned short* vb  = take(2097152);  // [4096][512]
  unsigned short* vtb = take(2097152);  // [2*512][2048]
  unsigned short* ctx = take(8388608);  // [4096][2048]

  cvt_f32_bf16<<<4096, 256, 0, stream>>>(h, hb, 8388608L);
  transpose_to_bf16<float><<<dim3(64, 64, 1), 256, 0, stream>>>(Wq, WqT, 2048, 2048);
  transpose_to_bf16<float><<<dim3(16, 64, 1), 256, 0, stream>>>(Wl, WlT, 2048, 512);
  transpose_to_bf16<float><<<dim3(16, 16, 1), 256, 0, stream>>>(Wk, WkT, 512, 512);
  transpose_to_bf16<float><<<dim3(16, 16, 1), 256, 0, stream>>>(Wv, WvT, 512, 512);
  transpose_to_bf16<float><<<dim3(64, 64, 1), 256, 0, stream>>>(Wo, WoT, 2048, 2048);

  const float scale = 0.08838834764831845f;  // 1/sqrt(128), folded into q
  gemm_bt_256<0><<<dim3(16, 16), 512, 0, stream>>>(hb, WqT, bq, qb, M, 2048, 2048, scale);
  gemm_bt<0><<<dim3(4, 32), 256, 0, stream>>>(hb, WlT, bl, lat, M, 512, 2048, 1.0f);
  gemm_bt<0><<<dim3(4, 32), 256, 0, stream>>>(lat, WkT, bk, kb, M, 512, 512, 1.0f);
  gemm_bt<0><<<dim3(4, 32), 256, 0, stream>>>(lat, WvT, bv, vb, M, 512, 512, 1.0f);

  transpose_to_bf16<unsigned short><<<dim3(16, 64, 2), 256, 0, stream>>>(vb, vtb, 2048, 512);

  attn_kernel<<<dim3(16, 16, 2), 256, 0, stream>>>(qb, kb, vtb, ctx);

  gemm_bt_256<1><<<dim3(16, 16), 512, 0, stream>>>(ctx, WoT, bo, out, M, 2048, 2048, 1.0f);
}

// Round 8
// 277.756 us; speedup vs baseline: 2.4025x; 1.0206x over previous
//
#include <hip/hip_runtime.h>
#include <stdint.h>

// GroupedQueryLatentAttention on MI355X (gfx950).
// B=2 S=2048 HID=2048 HEADS=16 D=128 GROUPS=4 LATENT=512 KV=512.
// R8: attn = bit-exact proven R4 kernel (KVBLK=64, 2 q-subtiles/wave) with
// only (a) K source stride 512->1024 (fused kv buffer) and (b) setprio
// around MFMA clusters. k&v projections fused into one N=1024 GEMM.
// R6/R7's KVBLK=32 restructure is abandoned (bisected: it was the bug).

#define DEV static __device__ __forceinline__

using short8 = __attribute__((ext_vector_type(8))) short;
using f32x4  = __attribute__((ext_vector_type(4))) float;

typedef __attribute__((address_space(1))) void gvoid;
typedef __attribute__((address_space(3))) void lvoid;

DEV unsigned short f2b(float f) {
  unsigned u = __builtin_bit_cast(unsigned, f);
  unsigned r = (u + 0x7fffu + ((u >> 16) & 1u)) >> 16;
  return (unsigned short)r;
}
DEV float b2f(unsigned short s) {
  unsigned u = ((unsigned)s) << 16;
  return __builtin_bit_cast(float, u);
}
DEV float as_f32(float v) { return v; }
DEV float as_f32(unsigned short v) { return b2f(v); }

DEV unsigned pack2bf(float lo, float hi) {
  return (unsigned)f2b(lo) | ((unsigned)f2b(hi) << 16);
}

// async global->LDS, 16B per lane. LDS dest resolves to firstlane base + lane*16.
DEV void async16(const void* g, void* l) {
  __builtin_amdgcn_global_load_lds((gvoid*)(uintptr_t)g,
                                   (lvoid*)(uint32_t)(uintptr_t)l, 16, 0, 0);
}

DEV f32x4 mfma16(short8 a, short8 b, f32x4 c) {
  return __builtin_amdgcn_mfma_f32_16x16x32_bf16(a, b, c, 0, 0, 0);
}

// ---------------- elementwise fp32 -> bf16 ----------------
__global__ __launch_bounds__(256) void cvt_f32_bf16(
    const float* __restrict__ in, unsigned short* __restrict__ out, long n) {
  long i = ((long)blockIdx.x * 256 + threadIdx.x) * 8;
  if (i >= n) return;
  float4 a = *(const float4*)(in + i);
  float4 b = *(const float4*)(in + i + 4);
  short8 o;
  o[0] = (short)f2b(a.x); o[1] = (short)f2b(a.y);
  o[2] = (short)f2b(a.z); o[3] = (short)f2b(a.w);
  o[4] = (short)f2b(b.x); o[5] = (short)f2b(b.y);
  o[6] = (short)f2b(b.z); o[7] = (short)f2b(b.w);
  *(short8*)(out + i) = o;
}

// ---------------- transpose [R][C] -> [C][R], out bf16 ----------------
template <typename TIN>
__global__ __launch_bounds__(256) void transpose_to_bf16(
    const TIN* __restrict__ in, unsigned short* __restrict__ out, int R, int C) {
  __shared__ float tile[32][33];
  size_t batch = (size_t)blockIdx.z * (size_t)R * C;
  int bc = blockIdx.x * 32, br = blockIdx.y * 32;
  int tx = threadIdx.x & 31, ty0 = threadIdx.x >> 5;
#pragma unroll
  for (int ty = ty0; ty < 32; ty += 8)
    tile[ty][tx] = as_f32(in[batch + (size_t)(br + ty) * C + bc + tx]);
  __syncthreads();
#pragma unroll
  for (int ty = ty0; ty < 32; ty += 8)
    out[batch + (size_t)(bc + ty) * R + br + tx] = f2b(tile[tx][ty]);
}

// ---------------- V-part transpose: kvb[b*2048+s][1024] cols 512.. -> vt ----
__global__ __launch_bounds__(256) void transpose_v(
    const unsigned short* __restrict__ in, unsigned short* __restrict__ out) {
  __shared__ float tile[32][33];
  int b = blockIdx.z;
  int bc = blockIdx.x * 32;  // v-col within 512
  int br = blockIdx.y * 32;  // s
  const unsigned short* ip = in + (size_t)b * 2048 * 1024 + 512;
  unsigned short* op = out + (size_t)b * 512 * 2048;
  int tx = threadIdx.x & 31, ty0 = threadIdx.x >> 5;
#pragma unroll
  for (int ty = ty0; ty < 32; ty += 8)
    tile[ty][tx] = b2f(ip[(size_t)(br + ty) * 1024 + bc + tx]);
  __syncthreads();
#pragma unroll
  for (int ty = ty0; ty < 32; ty += 8)
    op[(size_t)(bc + ty) * 2048 + br + tx] = f2b(tile[tx][ty]);
}

// ---------------- GEMM 128x128: C = A * Bt^T + bias ----------------
template <int OUT_F32>
__global__ __launch_bounds__(256) void gemm_bt(
    const unsigned short* __restrict__ A, const unsigned short* __restrict__ Bt,
    const float* __restrict__ bias, void* __restrict__ Cout,
    int M, int N, int K, float scale) {
  __shared__ unsigned short As[128 * 32];
  __shared__ unsigned short Bs[128 * 32];
  int tid = threadIdx.x;
  int lane = tid & 63, wave = tid >> 6;
  int wr = wave >> 1, wc = wave & 1;
  int lq = lane & 15, grp = lane >> 4;
  int brow = blockIdx.y * 128, bcol = blockIdx.x * 128;

  f32x4 acc[4][4] = {};

  for (int k0 = 0; k0 < K; k0 += 32) {
    {
      int e0 = tid * 8;
      int r0 = e0 >> 5, c0 = e0 & 31;
      async16(A + (size_t)(brow + r0) * K + k0 + c0, As + e0);
      async16(Bt + (size_t)(bcol + r0) * K + k0 + c0, Bs + e0);
      int e1 = (256 + tid) * 8;
      int r1 = e1 >> 5, c1 = e1 & 31;
      async16(A + (size_t)(brow + r1) * K + k0 + c1, As + e1);
      async16(Bt + (size_t)(bcol + r1) * K + k0 + c1, Bs + e1);
    }
    __syncthreads();

    short8 af[4], bf[4];
#pragma unroll
    for (int m = 0; m < 4; m++)
      af[m] = *(const short8*)(As + (wr * 64 + m * 16 + lq) * 32 + grp * 8);
#pragma unroll
    for (int n = 0; n < 4; n++)
      bf[n] = *(const short8*)(Bs + (wc * 64 + n * 16 + lq) * 32 + grp * 8);
#pragma unroll
    for (int m = 0; m < 4; m++)
#pragma unroll
      for (int n = 0; n < 4; n++)
        acc[m][n] = mfma16(af[m], bf[n], acc[m][n]);
    __syncthreads();
  }

#pragma unroll
  for (int n = 0; n < 4; n++) {
    int col = bcol + wc * 64 + n * 16 + lq;
    float bv = bias[col];
#pragma unroll
    for (int m = 0; m < 4; m++) {
#pragma unroll
      for (int r = 0; r < 4; r++) {
        int row = brow + wr * 64 + m * 16 + grp * 4 + r;
        float v = (acc[m][n][r] + bv) * scale;
        if (OUT_F32)
          ((float*)Cout)[(size_t)row * N + col] = v;
        else
          ((unsigned short*)Cout)[(size_t)row * N + col] = f2b(v);
      }
    }
  }
}

// ---------------- GEMM 256x128x64, 8 waves, phase-interleaved (R4) ---------
template <int OUT_F32>
__global__ __launch_bounds__(512, 2) void gemm_bt_256(
    const unsigned short* __restrict__ A, const unsigned short* __restrict__ Bt,
    const float* __restrict__ bias, void* __restrict__ Cout,
    int M, int N, int K, float scale) {
  __shared__ __align__(1024) unsigned short As[2][16384];
  __shared__ __align__(1024) unsigned short Bs[2][8192];
  const int tid = threadIdx.x;
  const int lane = tid & 63, wave = tid >> 6;
  const int wr = wave >> 1, wc = wave & 1;
  const int lq = lane & 15, grp = lane >> 4;

  const int gx = gridDim.x;
  int nwg = gx * gridDim.y;
  int bid = blockIdx.y * gx + blockIdx.x;
  int wgid = (bid & 7) * (nwg >> 3) + (bid >> 3);
  int bx = wgid % gx, by = wgid / gx;
  const int brow = by * 256, bcol = bx * 128;

#define MKSLOT(db, mat, rb)                                            \
  ({ int d_ = (db) + lane * 16;                                        \
     int L_ = d_ ^ (((d_ >> 9) & 1) << 5);                             \
     (mat) + (size_t)((rb) + (L_ >> 7)) * K + ((L_ & 127) >> 1); })
  const int dbA0 = wave * 1024, dbA1 = dbA0 + 8192, dbA2 = dbA0 + 16384,
            dbA3 = dbA0 + 24576;
  const int dbB0 = (wave < 4) ? wave * 1024 : 8192 + (wave - 4) * 1024;
  const int dbB1 = dbB0 + 4096;
  const unsigned short* srcA0 = MKSLOT(dbA0, A, brow);
  const unsigned short* srcA1 = MKSLOT(dbA1, A, brow);
  const unsigned short* srcA2 = MKSLOT(dbA2, A, brow);
  const unsigned short* srcA3 = MKSLOT(dbA3, A, brow);
  const unsigned short* srcB0 = MKSLOT(dbB0, Bt, bcol);
  const unsigned short* srcB1 = MKSLOT(dbB1, Bt, bcol);
  char* dstA0 = (char*)&As[0][0] + dbA0 + lane * 16;
  char* dstA1 = (char*)&As[0][0] + dbA1 + lane * 16;
  char* dstA2 = (char*)&As[0][0] + dbA2 + lane * 16;
  char* dstA3 = (char*)&As[0][0] + dbA3 + lane * 16;
  char* dstB0 = (char*)&Bs[0][0] + dbB0 + lane * 16;
  char* dstB1 = (char*)&Bs[0][0] + dbB1 + lane * 16;
#define STA(i, b, k0) async16(srcA##i + (k0), dstA##i + (b) * 32768)
#define STB(i, b, k0) async16(srcB##i + (k0), dstB##i + (b) * 16384)

  auto ldA = [&](int cur, int row, int kk) -> short8 {
    int p = row * 128 + kk * 64 + grp * 16;
    p ^= ((p >> 9) & 1) << 5;
    return *(const short8*)((const char*)&As[cur][0] + p);
  };
  auto ldB = [&](int cur, int row, int kk) -> short8 {
    int p = row * 128 + kk * 64 + grp * 16;
    p ^= ((p >> 9) & 1) << 5;
    return *(const short8*)((const char*)&Bs[cur][0] + p);
  };

  f32x4 acc[4][4] = {};
  short8 af[4][2], bf[4][2];
  const int NT = K >> 6;

  STA(0, 0, 0); STA(1, 0, 0); STA(2, 0, 0); STA(3, 0, 0);
  STB(0, 0, 0); STB(1, 0, 0);
  asm volatile("s_waitcnt vmcnt(1)" ::: "memory");
  __builtin_amdgcn_s_barrier();

  for (int t = 0; t < NT; ++t) {
    const int cur = t & 1, nb = cur ^ 1;
    const bool pf = (t + 1 < NT);
    const int k0n = (t + 1) << 6;

#pragma unroll
    for (int m = 0; m < 4; m++) {
      af[m][0] = ldA(cur, wr * 64 + m * 16 + lq, 0);
      af[m][1] = ldA(cur, wr * 64 + m * 16 + lq, 1);
    }
#pragma unroll
    for (int n = 0; n < 2; n++) {
      bf[n][0] = ldB(cur, wc * 64 + n * 16 + lq, 0);
      bf[n][1] = ldB(cur, wc * 64 + n * 16 + lq, 1);
    }
    if (pf) { STA(0, nb, k0n); STA(1, nb, k0n); STA(2, nb, k0n); }
    __builtin_amdgcn_s_barrier();
    __builtin_amdgcn_s_setprio(1);
#pragma unroll
    for (int m = 0; m < 4; m++)
#pragma unroll
      for (int n = 0; n < 2; n++) {
        acc[m][n] = mfma16(af[m][0], bf[n][0], acc[m][n]);
        acc[m][n] = mfma16(af[m][1], bf[n][1], acc[m][n]);
      }
    __builtin_amdgcn_s_setprio(0);
    __builtin_amdgcn_s_barrier();

    if (pf) {
      STA(3, nb, k0n); STB(0, nb, k0n); STB(1, nb, k0n);
      asm volatile("s_waitcnt vmcnt(6)" ::: "memory");
    } else {
      asm volatile("s_waitcnt vmcnt(0)" ::: "memory");
    }
    __builtin_amdgcn_s_barrier();
#pragma unroll
    for (int n = 0; n < 2; n++) {
      bf[2 + n][0] = ldB(cur, wc * 64 + (2 + n) * 16 + lq, 0);
      bf[2 + n][1] = ldB(cur, wc * 64 + (2 + n) * 16 + lq, 1);
    }
    __builtin_amdgcn_s_setprio(1);
#pragma unroll
    for (int m = 0; m < 4; m++)
#pragma unroll
      for (int n = 2; n < 4; n++) {
        acc[m][n] = mfma16(af[m][0], bf[n][0], acc[m][n]);
        acc[m][n] = mfma16(af[m][1], bf[n][1], acc[m][n]);
      }
    __builtin_amdgcn_s_setprio(0);
    if (pf) {
      asm volatile("s_waitcnt vmcnt(1)" ::: "memory");
    }
    __builtin_amdgcn_s_barrier();
  }

#pragma unroll
  for (int n = 0; n < 4; n++) {
    int col = bcol + wc * 64 + n * 16 + lq;
    float bv = bias[col];
#pragma unroll
    for (int m = 0; m < 4; m++) {
#pragma unroll
      for (int r = 0; r < 4; r++) {
        int row = brow + wr * 64 + m * 16 + grp * 4 + r;
        float v = (acc[m][n][r] + bv) * scale;
        if (OUT_F32)
          ((float*)Cout)[(size_t)row * N + col] = v;
        else
          ((unsigned short*)Cout)[(size_t)row * N + col] = f2b(v);
      }
    }
  }
#undef STA
#undef STB
#undef MKSLOT
}

// ---------------- flash attention (proven R4 structure) ----------------
// grid (S/128, HEADS, B), block 256 = 4 waves; each wave owns 32 q-rows
// (2 sub-tiles of 16). KVBLK=64. K/V staged in LDS, fragment-packed.
// Changes vs R4: K source = fused kvb (row stride 1024, cols 0..511);
// setprio(1) around MFMA clusters.
__global__ __launch_bounds__(256, 2) void attn_kernel(
    const unsigned short* __restrict__ q,   // [B*S][2048], pre-scaled
    const unsigned short* __restrict__ kv,  // [B*S][1024]; K = cols 0..511
    const unsigned short* __restrict__ vt,  // [(b*4+g)*128 + d][2048]
    unsigned short* __restrict__ ctx) {     // [B*S][2048]
  __shared__ unsigned short KV[2][32][512];
  const int lane = threadIdx.x & 63, wave = threadIdx.x >> 6;
  const int lq = lane & 15, grp = lane >> 4;
  const int h = blockIdx.y, b = blockIdx.z, g = h >> 2;
  const int qbase = blockIdx.x * 128 + wave * 32;

  short8 qf[2][4];
#pragma unroll
  for (int qs = 0; qs < 2; qs++) {
    const unsigned short* qp =
        q + ((size_t)(b * 2048 + qbase + qs * 16 + lq)) * 2048 + h * 128 + grp * 8;
#pragma unroll
    for (int c = 0; c < 4; c++) qf[qs][c] = *(const short8*)(qp + c * 32);
  }

  f32x4 o[2][8] = {};
  float mrun[2] = {-3.0e38f, -3.0e38f};
  float lsum[2] = {0.f, 0.f};

  const int kvperm = (lq >> 2) * 8 + (lq & 3);
  const unsigned short* kB = kv + (size_t)b * 2048 * 1024 + g * 128 + grp * 8;
  const unsigned short* vB =
      vt + ((size_t)((b * 4 + g) * 128 + lq)) * 2048 + grp * 8;
  const int fbase = wave * 8;
  unsigned short* dstb = &KV[0][fbase][0] + lane * 8;

  auto stage = [&](int bn, int kv0) {
    unsigned short* dst = dstb + bn * 16384;
    if (fbase < 16) {
#pragma unroll
      for (int j = 0; j < 8; j++) {
        int f = fbase + j, t = f >> 2, c = f & 3;
        const unsigned short* src =
            kB + (size_t)(kv0 + (t >> 1) * 32 + (t & 1) * 4 + kvperm) * 1024 + c * 32;
        async16(src, dst + j * 512);
      }
    } else {
#pragma unroll
      for (int j = 0; j < 8; j++) {
        int f = fbase - 16 + j, d0 = f >> 1, u = f & 1;
        const unsigned short* src = vB + (size_t)(d0 * 16) * 2048 + kv0 + u * 32;
        async16(src, dst + j * 512);
      }
    }
  };

  stage(0, 0);
  int buf = 0;
  for (int it = 0; it < 32; ++it) {
    __syncthreads();
    if (it < 31) stage(buf ^ 1, (it + 1) * 64);
    const unsigned short* Kb = &KV[buf][0][0] + lane * 8;

    f32x4 s[2][4] = {};
    __builtin_amdgcn_s_setprio(1);
#pragma unroll
    for (int c = 0; c < 4; c++) {
      short8 kf0 = *(const short8*)(Kb + (0 + c) * 512);
      short8 kf1 = *(const short8*)(Kb + (4 + c) * 512);
      short8 kf2 = *(const short8*)(Kb + (8 + c) * 512);
      short8 kf3 = *(const short8*)(Kb + (12 + c) * 512);
#pragma unroll
      for (int qs = 0; qs < 2; qs++) {
        s[qs][0] = mfma16(kf0, qf[qs][c], s[qs][0]);
        s[qs][1] = mfma16(kf1, qf[qs][c], s[qs][1]);
        s[qs][2] = mfma16(kf2, qf[qs][c], s[qs][2]);
        s[qs][3] = mfma16(kf3, qf[qs][c], s[qs][3]);
      }
    }
    __builtin_amdgcn_s_setprio(0);

    float lm[2];
#pragma unroll
    for (int qs = 0; qs < 2; qs++) {
      float a = fmaxf(fmaxf(s[qs][0][0], s[qs][0][1]), fmaxf(s[qs][0][2], s[qs][0][3]));
      float bm = fmaxf(fmaxf(s[qs][1][0], s[qs][1][1]), fmaxf(s[qs][1][2], s[qs][1][3]));
      float cm = fmaxf(fmaxf(s[qs][2][0], s[qs][2][1]), fmaxf(s[qs][2][2], s[qs][2][3]));
      float dm = fmaxf(fmaxf(s[qs][3][0], s[qs][3][1]), fmaxf(s[qs][3][2], s[qs][3][3]));
      lm[qs] = fmaxf(fmaxf(a, bm), fmaxf(cm, dm));
    }
    if (__any((lm[0] > mrun[0] + 8.f) || (lm[1] > mrun[1] + 8.f))) {
#pragma unroll
      for (int qs = 0; qs < 2; qs++) {
        float t0 = fmaxf(lm[qs], __shfl_xor(lm[qs], 16));
        t0 = fmaxf(t0, __shfl_xor(t0, 32));
        float mnew = fmaxf(mrun[qs], t0);
        float al = __expf(mrun[qs] - mnew);
        lsum[qs] *= al;
        mrun[qs] = mnew;
        float a0 = __shfl(al, grp * 4 + 0), a1 = __shfl(al, grp * 4 + 1);
        float a2 = __shfl(al, grp * 4 + 2), a3 = __shfl(al, grp * 4 + 3);
#pragma unroll
        for (int d0 = 0; d0 < 8; d0++) {
          o[qs][d0][0] *= a0; o[qs][d0][1] *= a1;
          o[qs][d0][2] *= a2; o[qs][d0][3] *= a3;
        }
      }
    }

    short8 pf[2][2];
#pragma unroll
    for (int qs = 0; qs < 2; qs++) {
      float m = mrun[qs], ps = 0.f;
      union { short8 v; unsigned w[4]; } pk0, pk1;
#pragma unroll
      for (int t = 0; t < 4; t++) {
        float e0 = __expf(s[qs][t][0] - m);
        float e1 = __expf(s[qs][t][1] - m);
        float e2 = __expf(s[qs][t][2] - m);
        float e3 = __expf(s[qs][t][3] - m);
        ps += (e0 + e1) + (e2 + e3);
        unsigned w0 = pack2bf(e0, e1), w1 = pack2bf(e2, e3);
        if (t == 0) { pk0.w[0] = w0; pk0.w[1] = w1; }
        else if (t == 1) { pk0.w[2] = w0; pk0.w[3] = w1; }
        else if (t == 2) { pk1.w[0] = w0; pk1.w[1] = w1; }
        else { pk1.w[2] = w0; pk1.w[3] = w1; }
      }
      lsum[qs] += ps;
      pf[qs][0] = pk0.v;
      pf[qs][1] = pk1.v;
    }

    const unsigned short* Vb = Kb + 16 * 512;
    __builtin_amdgcn_s_setprio(1);
#pragma unroll
    for (int d0 = 0; d0 < 8; d0++) {
      short8 v0 = *(const short8*)(Vb + (d0 * 2 + 0) * 512);
      short8 v1 = *(const short8*)(Vb + (d0 * 2 + 1) * 512);
#pragma unroll
      for (int qs = 0; qs < 2; qs++) {
        o[qs][d0] = mfma16(pf[qs][0], v0, o[qs][d0]);
        o[qs][d0] = mfma16(pf[qs][1], v1, o[qs][d0]);
      }
    }
    __builtin_amdgcn_s_setprio(0);
    buf ^= 1;
  }

  unsigned short* cp = ctx + ((size_t)(b * 2048 + qbase)) * 2048 + h * 128;
#pragma unroll
  for (int qs = 0; qs < 2; qs++) {
    float l = lsum[qs];
    l += __shfl_xor(l, 16);
    l += __shfl_xor(l, 32);
    float ri = 1.0f / l;
    float r0 = __shfl(ri, grp * 4 + 0), r1 = __shfl(ri, grp * 4 + 1);
    float r2 = __shfl(ri, grp * 4 + 2), r3 = __shfl(ri, grp * 4 + 3);
#pragma unroll
    for (int d0 = 0; d0 < 8; d0++) {
      int col = d0 * 16 + lq;
      cp[(size_t)(qs * 16 + grp * 4 + 0) * 2048 + col] = f2b(o[qs][d0][0] * r0);
      cp[(size_t)(qs * 16 + grp * 4 + 1) * 2048 + col] = f2b(o[qs][d0][1] * r1);
      cp[(size_t)(qs * 16 + grp * 4 + 2) * 2048 + col] = f2b(o[qs][d0][2] * r2);
      cp[(size_t)(qs * 16 + grp * 4 + 3) * 2048 + col] = f2b(o[qs][d0][3] * r3);
    }
  }
}

// ---------------- host ----------------
extern "C" void kernel_launch(void* const* d_in, const int* in_sizes, int n_in,
                              void* d_out, int out_size, void* d_ws, size_t ws_size,
                              hipStream_t stream) {
  const float* h  = (const float*)d_in[0];
  const float* Wq = (const float*)d_in[1];
  const float* bq = (const float*)d_in[2];
  const float* Wl = (const float*)d_in[3];
  const float* bl = (const float*)d_in[4];
  const float* Wk = (const float*)d_in[5];
  const float* bk = (const float*)d_in[6];
  const float* Wv = (const float*)d_in[7];
  const float* bv = (const float*)d_in[8];
  const float* Wo = (const float*)d_in[9];
  const float* bo = (const float*)d_in[10];
  float* out = (float*)d_out;

  const int M = 4096;  // B*S

  char* w = (char*)d_ws;
  auto take = [&](size_t elems) {
    void* p = (void*)w;
    w += (elems * 2 + 255) & ~(size_t)255;
    return (unsigned short*)p;
  };
  unsigned short* hb   = take(8388608);  // [4096][2048]
  unsigned short* WqT  = take(4194304);  // [2048][2048]
  unsigned short* WlT  = take(1048576);  // [512][2048]
  unsigned short* WkvT = take(524288);   // [1024][512]: rows 0..511 Wk^T, 512.. Wv^T
  unsigned short* WoT  = take(4194304);  // [2048][2048]
  unsigned short* qb   = take(8388608);  // [4096][2048]
  unsigned short* lat  = take(2097152);  // [4096][512]
  unsigned short* kvb  = take(4194304);  // [4096][1024]: cols 0..511 K, 512.. V
  unsigned short* vtb  = take(2097152);  // [2*512][2048]
  unsigned short* ctx  = take(8388608);  // [4096][2048]
  float* bkv = (float*)take(2048);       // 1024 f32

  cvt_f32_bf16<<<4096, 256, 0, stream>>>(h, hb, 8388608L);
  transpose_to_bf16<float><<<dim3(64, 64, 1), 256, 0, stream>>>(Wq, WqT, 2048, 2048);
  transpose_to_bf16<float><<<dim3(16, 64, 1), 256, 0, stream>>>(Wl, WlT, 2048, 512);
  transpose_to_bf16<float><<<dim3(16, 16, 1), 256, 0, stream>>>(Wk, WkvT, 512, 512);
  transpose_to_bf16<float><<<dim3(16, 16, 1), 256, 0, stream>>>(Wv, WkvT + 262144, 512, 512);
  transpose_to_bf16<float><<<dim3(64, 64, 1), 256, 0, stream>>>(Wo, WoT, 2048, 2048);
  (void)hipMemcpyAsync(bkv, bk, 512 * sizeof(float), hipMemcpyDeviceToDevice, stream);
  (void)hipMemcpyAsync(bkv + 512, bv, 512 * sizeof(float), hipMemcpyDeviceToDevice, stream);

  const float scale = 0.08838834764831845f;  // 1/sqrt(128), folded into q
  gemm_bt_256<0><<<dim3(16, 16), 512, 0, stream>>>(hb, WqT, bq, qb, M, 2048, 2048, scale);
  gemm_bt<0><<<dim3(4, 32), 256, 0, stream>>>(hb, WlT, bl, lat, M, 512, 2048, 1.0f);
  gemm_bt<0><<<dim3(8, 32), 256, 0, stream>>>(lat, WkvT, bkv, kvb, M, 1024, 512, 1.0f);

  transpose_v<<<dim3(16, 64, 2), 256, 0, stream>>>(kvb, vtb);

  attn_kernel<<<dim3(16, 16, 2), 256, 0, stream>>>(qb, kvb, vtb, ctx);

  gemm_bt_256<1><<<dim3(16, 16), 512, 0, stream>>>(ctx, WoT, bo, out, M, 2048, 2048, 1.0f);
}